// Round 2
// baseline (2880.946 us; speedup 1.0000x reference)
//
#include <hip/hip_runtime.h>
#include <hip/hip_bf16.h>
#include <math.h>

#define BN    32
#define NTOK  785
#define GH    28
#define GW    28
#define DIM   768
#define QKVD  2304
#define NH    8
#define HD    96
#define MROWS (BN*NTOK)   // 25120

typedef __hip_bfloat16 bf16;

// ---------------------------------------------------------------------------
// K1: qkv GEMM. A=x fp32 (M x 768), B=W_qkv (768 x 2304), fp32 accumulate,
// outputs split by column into separate bf16 q/k/v buffers (each M x 768).
// 64x64 tile, 4x4 per thread.
// ---------------------------------------------------------------------------
__global__ __launch_bounds__(256)
void gemm_qkv_kernel(const float* __restrict__ A, const float* __restrict__ Bm,
                     const float* __restrict__ bias,
                     bf16* __restrict__ q, bf16* __restrict__ k, bf16* __restrict__ v) {
    const int M = MROWS, N = QKVD, K = DIM;
    __shared__ float As[16][68];   // [k][m]
    __shared__ float Bs[16][64];   // [k][n]
    const int tx = threadIdx.x, ty = threadIdx.y;
    const int t = ty * 16 + tx;
    const int row0 = blockIdx.y * 64;
    const int col0 = blockIdx.x * 64;
    float acc[4][4] = {};
    for (int k0 = 0; k0 < K; k0 += 16) {
        #pragma unroll
        for (int i = 0; i < 4; ++i) {
            int idx = t + i * 256;
            int r = idx >> 4, ck = idx & 15;
            int row = row0 + r;
            As[ck][r] = (row < M) ? A[(size_t)row * K + k0 + ck] : 0.f;
        }
        #pragma unroll
        for (int i = 0; i < 4; ++i) {
            int idx = t + i * 256;
            int r = idx >> 6, c = idx & 63;
            Bs[r][c] = Bm[(size_t)(k0 + r) * N + col0 + c];
        }
        __syncthreads();
        #pragma unroll
        for (int kk = 0; kk < 16; ++kk) {
            float4 a4 = *(const float4*)&As[kk][ty * 4];
            float4 b4 = *(const float4*)&Bs[kk][tx * 4];
            float av[4] = {a4.x, a4.y, a4.z, a4.w};
            float bv[4] = {b4.x, b4.y, b4.z, b4.w};
            #pragma unroll
            for (int i = 0; i < 4; ++i)
                #pragma unroll
                for (int j = 0; j < 4; ++j)
                    acc[i][j] += av[i] * bv[j];
        }
        __syncthreads();
    }
    float4 bb = *(const float4*)&bias[col0 + tx * 4];
    float bv[4] = {bb.x, bb.y, bb.z, bb.w};
    // column-segment select (64-wide blocks never straddle the 768 boundaries)
    bf16* seg; int cbase = col0;
    if (cbase < DIM)            { seg = q; }
    else if (cbase < 2 * DIM)   { seg = k; cbase -= DIM; }
    else                        { seg = v; cbase -= 2 * DIM; }
    #pragma unroll
    for (int i = 0; i < 4; ++i) {
        int row = row0 + ty * 4 + i;
        if (row < M) {
            #pragma unroll
            for (int j = 0; j < 4; ++j)
                seg[(size_t)row * DIM + cbase + tx * 4 + j] =
                    __float2bfloat16(acc[i][j] + bv[j]);
        }
    }
}

// ---------------------------------------------------------------------------
// K2: per-(b,c) softmax stats over 785 tokens of k (bf16, row stride 768)
// ---------------------------------------------------------------------------
__global__ __launch_bounds__(256)
void softmax_stats_kernel(const bf16* __restrict__ k,
                          float* __restrict__ stat_m, float* __restrict__ stat_is) {
    int b = blockIdx.y;
    int c = blockIdx.x * 64 + threadIdx.x;
    int ty = threadIdx.y;
    const bf16* base = k + (size_t)b * NTOK * DIM + c;
    float m = -1e30f, s = 0.f;
    for (int n = ty; n < NTOK; n += 4) {
        float kv = __bfloat162float(base[(size_t)n * DIM]);
        float nm = fmaxf(m, kv);
        s = s * __expf(m - nm) + __expf(kv - nm);
        m = nm;
    }
    __shared__ float sm[4][64], ss[4][64];
    sm[ty][threadIdx.x] = m; ss[ty][threadIdx.x] = s;
    __syncthreads();
    if (ty == 0) {
        float M = sm[0][threadIdx.x];
        #pragma unroll
        for (int i = 1; i < 4; ++i) M = fmaxf(M, sm[i][threadIdx.x]);
        float S = 0.f;
        #pragma unroll
        for (int i = 0; i < 4; ++i) S += ss[i][threadIdx.x] * __expf(sm[i][threadIdx.x] - M);
        stat_m[b * DIM + c] = M;
        stat_is[b * DIM + c] = 1.f / S;
    }
}

// ---------------------------------------------------------------------------
// K3: attn[b,h,d,e] = sum_n softmax(k)[n,d] * v[n,e]   (96x96 per (b,h))
// ---------------------------------------------------------------------------
__global__ __launch_bounds__(256)
void attn_kernel(const bf16* __restrict__ k, const bf16* __restrict__ v,
                 const float* __restrict__ stat_m, const float* __restrict__ stat_is,
                 float* __restrict__ attn) {
    int h = blockIdx.x, b = blockIdx.y;
    int tx = threadIdx.x, ty = threadIdx.y;
    int t = ty * 16 + tx;
    __shared__ float ek[16][96], vv[16][96];
    __shared__ float smM[96], smIS[96];
    if (t < 96) { smM[t] = stat_m[b * DIM + h * HD + t]; smIS[t] = stat_is[b * DIM + h * HD + t]; }
    __syncthreads();
    float acc[6][6] = {};
    const bf16* kbase = k + (size_t)b * NTOK * DIM + h * HD;
    const bf16* vbase = v + (size_t)b * NTOK * DIM + h * HD;
    for (int n0 = 0; n0 < NTOK; n0 += 16) {
        #pragma unroll
        for (int i = 0; i < 6; ++i) {
            int idx = t + i * 256;           // 0..1535 = 16 tokens x 96 ch
            int nl = idx / 96, c = idx % 96;
            int n = n0 + nl;
            float ekv = 0.f, vvv = 0.f;
            if (n < NTOK) {
                float kv = __bfloat162float(kbase[(size_t)n * DIM + c]);
                ekv = __expf(kv - smM[c]) * smIS[c];
                vvv = __bfloat162float(vbase[(size_t)n * DIM + c]);
            }
            ek[nl][c] = ekv; vv[nl][c] = vvv;
        }
        __syncthreads();
        #pragma unroll
        for (int nl = 0; nl < 16; ++nl) {
            float ka[6], vb[6];
            #pragma unroll
            for (int i = 0; i < 6; ++i) ka[i] = ek[nl][tx * 6 + i];
            #pragma unroll
            for (int j = 0; j < 6; ++j) vb[j] = vv[nl][ty * 6 + j];
            #pragma unroll
            for (int i = 0; i < 6; ++i)
                #pragma unroll
                for (int j = 0; j < 6; ++j)
                    acc[i][j] += ka[i] * vb[j];
        }
        __syncthreads();
    }
    float* abase = attn + ((size_t)(b * NH + h)) * HD * HD;
    #pragma unroll
    for (int i = 0; i < 6; ++i)
        #pragma unroll
        for (int j = 0; j < 6; ++j)
            abase[(size_t)(tx * 6 + i) * HD + ty * 6 + j] = acc[i][j];
}

// ---------------------------------------------------------------------------
// K4: depthwise-conv CRPE of v image tokens -> o[b,n,c] (rp, bf16); CLS row -> 0
// ---------------------------------------------------------------------------
__global__ __launch_bounds__(256)
void crpe_kernel(const bf16* __restrict__ v,
                 const float* __restrict__ w3, const float* __restrict__ b3,
                 const float* __restrict__ w5, const float* __restrict__ b5,
                 const float* __restrict__ w7, const float* __restrict__ b7,
                 bf16* __restrict__ o) {
    int b = blockIdx.z;
    int y = blockIdx.y;
    int c = blockIdx.x * 64 + threadIdx.x;
    int ty = threadIdx.y;
    int ks; const float* wp; float bias;
    if (c < 192)      { ks = 3; wp = w3 + c * 9;          bias = b3[c]; }
    else if (c < 480) { ks = 5; wp = w5 + (c - 192) * 25; bias = b5[c - 192]; }
    else              { ks = 7; wp = w7 + (c - 480) * 49; bias = b7[c - 480]; }
    const bf16* vbase = v + (size_t)b * NTOK * DIM + c;
    bf16* obase = o + (size_t)b * NTOK * DIM + c;
    if (y == 0 && ty == 0) obase[0] = __float2bfloat16(0.f);   // CLS token: rp = 0
    int r = ks >> 1;
    for (int x = ty; x < GW; x += 4) {
        float acc = bias;
        for (int ky = 0; ky < ks; ++ky) {
            int yy = y + ky - r;
            if (yy < 0 || yy >= GH) continue;
            for (int kx = 0; kx < ks; ++kx) {
                int xx = x + kx - r;
                if (xx < 0 || xx >= GW) continue;
                acc += wp[ky * ks + kx] *
                       __bfloat162float(vbase[(size_t)(1 + yy * GW + xx) * DIM]);
            }
        }
        obase[(size_t)(1 + y * GW + x) * DIM] = __float2bfloat16(acc);
    }
}

// ---------------------------------------------------------------------------
// K5: o[b,n,h*96+e] = scale * sum_d q[n,d] attn[d,e] + q[n,e] * rp (in-place)
// ---------------------------------------------------------------------------
__global__ __launch_bounds__(256)
void combine_kernel(const bf16* __restrict__ q, const float* __restrict__ attn,
                    bf16* __restrict__ o) {
    int h = blockIdx.x;
    int n0 = blockIdx.y * 64;
    int b = blockIdx.z;
    int tx = threadIdx.x, ty = threadIdx.y;
    int t = ty * 16 + tx;
    __shared__ float as[96][96];    // attn[d][e]
    __shared__ float qs[64][97];    // q tile, +1 pad
    const float* abase = attn + ((size_t)(b * NH + h)) * HD * HD;
    #pragma unroll
    for (int i = 0; i < 36; ++i) {
        int idx = t + i * 256;
        as[idx / 96][idx % 96] = abase[idx];
    }
    const bf16* qbase = q + (size_t)b * NTOK * DIM + h * HD;
    #pragma unroll
    for (int i = 0; i < 24; ++i) {
        int idx = t + i * 256;
        int rr = idx / 96, cc = idx % 96;
        int n = n0 + rr;
        qs[rr][cc] = (n < NTOK) ? __bfloat162float(qbase[(size_t)n * DIM + cc]) : 0.f;
    }
    __syncthreads();
    float acc[4][6] = {};
    for (int d = 0; d < 96; ++d) {
        float qa[4], ab[6];
        #pragma unroll
        for (int i = 0; i < 4; ++i) qa[i] = qs[ty * 4 + i][d];
        #pragma unroll
        for (int j = 0; j < 6; ++j) ab[j] = as[d][tx * 6 + j];
        #pragma unroll
        for (int i = 0; i < 4; ++i)
            #pragma unroll
            for (int j = 0; j < 6; ++j)
                acc[i][j] += qa[i] * ab[j];
    }
    const float scale = 0.10206207261596575f;  // 96^-0.5
    bf16* obase = o + (size_t)b * NTOK * DIM + h * HD;
    #pragma unroll
    for (int i = 0; i < 4; ++i) {
        int n = n0 + ty * 4 + i;
        if (n >= NTOK) continue;
        #pragma unroll
        for (int j = 0; j < 6; ++j) {
            int e = tx * 6 + j;
            size_t oa = (size_t)n * DIM + e;
            float rp = __bfloat162float(obase[oa]);   // K4 wrote rp here
            float qv = qs[ty * 4 + i][e];
            obase[oa] = __float2bfloat16(scale * acc[i][j] + qv * rp);
        }
    }
}

// ---------------------------------------------------------------------------
// K6: out = o(bf16) @ W_out + b_out  (fp32 accumulate/output)
// ---------------------------------------------------------------------------
__global__ __launch_bounds__(256)
void gemm_out_kernel(const bf16* __restrict__ A, const float* __restrict__ Bm,
                     const float* __restrict__ bias, float* __restrict__ C) {
    const int M = MROWS, N = DIM, K = DIM;
    __shared__ float As[16][68];
    __shared__ float Bs[16][64];
    const int tx = threadIdx.x, ty = threadIdx.y;
    const int t = ty * 16 + tx;
    const int row0 = blockIdx.y * 64;
    const int col0 = blockIdx.x * 64;
    float acc[4][4] = {};
    for (int k0 = 0; k0 < K; k0 += 16) {
        #pragma unroll
        for (int i = 0; i < 4; ++i) {
            int idx = t + i * 256;
            int r = idx >> 4, ck = idx & 15;
            int row = row0 + r;
            As[ck][r] = (row < M) ? __bfloat162float(A[(size_t)row * K + k0 + ck]) : 0.f;
        }
        #pragma unroll
        for (int i = 0; i < 4; ++i) {
            int idx = t + i * 256;
            int r = idx >> 6, c = idx & 63;
            Bs[r][c] = Bm[(size_t)(k0 + r) * N + col0 + c];
        }
        __syncthreads();
        #pragma unroll
        for (int kk = 0; kk < 16; ++kk) {
            float4 a4 = *(const float4*)&As[kk][ty * 4];
            float4 b4 = *(const float4*)&Bs[kk][tx * 4];
            float av[4] = {a4.x, a4.y, a4.z, a4.w};
            float bv[4] = {b4.x, b4.y, b4.z, b4.w};
            #pragma unroll
            for (int i = 0; i < 4; ++i)
                #pragma unroll
                for (int j = 0; j < 4; ++j)
                    acc[i][j] += av[i] * bv[j];
        }
        __syncthreads();
    }
    float4 bb = *(const float4*)&bias[col0 + tx * 4];
    float bv[4] = {bb.x, bb.y, bb.z, bb.w};
    #pragma unroll
    for (int i = 0; i < 4; ++i) {
        int row = row0 + ty * 4 + i;
        if (row < M) {
            float4 ov;
            ov.x = acc[i][0] + bv[0]; ov.y = acc[i][1] + bv[1];
            ov.z = acc[i][2] + bv[2]; ov.w = acc[i][3] + bv[3];
            *(float4*)&C[(size_t)row * N + col0 + tx * 4] = ov;
        }
    }
}

// ---------------------------------------------------------------------------
extern "C" void kernel_launch(void* const* d_in, const int* in_sizes, int n_in,
                              void* d_out, int out_size, void* d_ws, size_t ws_size,
                              hipStream_t stream) {
    const float* x     = (const float*)d_in[0];
    const float* W_qkv = (const float*)d_in[1];
    const float* b_qkv = (const float*)d_in[2];
    const float* W_out = (const float*)d_in[3];
    const float* b_out = (const float*)d_in[4];
    const float* w3    = (const float*)d_in[5];
    const float* cb3   = (const float*)d_in[6];
    const float* w5    = (const float*)d_in[7];
    const float* cb5   = (const float*)d_in[8];
    const float* w7    = (const float*)d_in[9];
    const float* cb7   = (const float*)d_in[10];
    float* out = (float*)d_out;

    // Workspace layout (125.4 MB total):
    //   q   bf16 M*768   38.6 MB
    //   k   bf16 M*768   38.6 MB   <- o (bf16) aliases this after K3 (k is dead)
    //   v   bf16 M*768   38.6 MB
    //   attn f32 32*8*96*96  9.4 MB
    //   stats f32 2*32*768   0.2 MB
    bf16* q = (bf16*)d_ws;
    bf16* k = q + (size_t)MROWS * DIM;
    bf16* v = k + (size_t)MROWS * DIM;
    float* attn    = (float*)(v + (size_t)MROWS * DIM);
    float* stat_m  = attn + (size_t)BN * NH * HD * HD;
    float* stat_is = stat_m + (size_t)BN * DIM;
    bf16* o = k;   // alias: k dead after attn_kernel

    dim3 bl(16, 16);
    gemm_qkv_kernel<<<dim3(QKVD / 64, (MROWS + 63) / 64), bl, 0, stream>>>(
        x, W_qkv, b_qkv, q, k, v);
    softmax_stats_kernel<<<dim3(12, BN), dim3(64, 4), 0, stream>>>(k, stat_m, stat_is);
    attn_kernel<<<dim3(NH, BN), bl, 0, stream>>>(k, v, stat_m, stat_is, attn);
    crpe_kernel<<<dim3(12, GH, BN), dim3(64, 4), 0, stream>>>(
        v, w3, cb3, w5, cb5, w7, cb7, o);
    combine_kernel<<<dim3(NH, 13, BN), bl, 0, stream>>>(q, attn, o);
    gemm_out_kernel<<<dim3(DIM / 64, (MROWS + 63) / 64), bl, 0, stream>>>(
        o, W_out, b_out, out);
}

// Round 3
// 1758.915 us; speedup vs baseline: 1.6379x; 1.6379x over previous
//
#include <hip/hip_runtime.h>
#include <hip/hip_bf16.h>
#include <math.h>

#define BN    32
#define NTOK  785
#define GH    28
#define GW    28
#define DIM   768
#define QKVD  2304
#define NH    8
#define HD    96
#define MROWS (BN*NTOK)   // 25120

typedef __hip_bfloat16 bf16;
typedef unsigned short ushort_t;
typedef short s16x8 __attribute__((ext_vector_type(8)));   // 8 bf16 = 4 VGPRs
typedef float f32x4 __attribute__((ext_vector_type(4)));   // MFMA acc

// ---------------------------------------------------------------------------
// helpers
// ---------------------------------------------------------------------------
__device__ __forceinline__ void gl2lds16(const void* g, void* l) {
    // 16B per lane, LDS dest = wave-uniform base + lane*16
    __builtin_amdgcn_global_load_lds(
        (__attribute__((address_space(1))) void*)const_cast<void*>(g),
        (__attribute__((address_space(3))) void*)l, 16, 0, 0);
}

__device__ __forceinline__ ushort_t f2bf(float f) {
    bf16 h = __float2bfloat16(f);
    return *(ushort_t*)&h;
}

__device__ __forceinline__ s16x8 cvt8(const float* p) {   // 8 fp32 (LDS) -> bf16x8
    float4 a = *(const float4*)p;
    float4 b = *(const float4*)(p + 4);
    union { s16x8 v; __hip_bfloat162 h[4]; } r;
    r.h[0] = __float22bfloat162_rn(make_float2(a.x, a.y));
    r.h[1] = __float22bfloat162_rn(make_float2(a.z, a.w));
    r.h[2] = __float22bfloat162_rn(make_float2(b.x, b.y));
    r.h[3] = __float22bfloat162_rn(make_float2(b.z, b.w));
    return r.v;
}

// ---------------------------------------------------------------------------
// K0: transpose-convert W[R][C] fp32 -> Wt[C][R] bf16
// ---------------------------------------------------------------------------
__global__ __launch_bounds__(256)
void transpose_bf16_kernel(const float* __restrict__ W, ushort_t* __restrict__ Wt,
                           int R, int C) {
    __shared__ float tile[32][33];
    int c0 = blockIdx.x * 32, r0 = blockIdx.y * 32;
    int tx = threadIdx.x, ty = threadIdx.y;   // 32 x 8
    #pragma unroll
    for (int i = 0; i < 4; ++i)
        tile[ty + i * 8][tx] = W[(size_t)(r0 + ty + i * 8) * C + c0 + tx];
    __syncthreads();
    #pragma unroll
    for (int i = 0; i < 4; ++i)
        Wt[(size_t)(c0 + ty + i * 8) * R + r0 + tx] = f2bf(tile[tx][ty + i * 8]);
}

// ---------------------------------------------------------------------------
// K1: qkv GEMM via MFMA. A = x fp32 (staged fp32, cvt on frag build),
// Bt = W_qkv^T bf16 [2304][768]. 128x128 tile, BK=32, 4 waves, 16x16x32 MFMA.
// Output split to q/k/v bf16.
// ---------------------------------------------------------------------------
__global__ __launch_bounds__(256)
void gemm_qkv_mfma(const float* __restrict__ A, const ushort_t* __restrict__ Bt,
                   const float* __restrict__ bias,
                   ushort_t* __restrict__ q, ushort_t* __restrict__ kk,
                   ushort_t* __restrict__ v) {
    const int M = MROWS, N = QKVD, K = DIM;
    __shared__ float    Asm[128 * 32];   // 16 KB, row-major [m][k]
    __shared__ ushort_t Bsm[128 * 32];   //  8 KB, row-major [n][k]
    const int tid  = threadIdx.x;
    const int wave = tid >> 6;
    const int lane = tid & 63;
    const int row0 = blockIdx.y * 128;
    const int col0 = blockIdx.x * 128;
    const int wm = wave >> 1, wn = wave & 1;
    const int q4 = lane >> 4, l15 = lane & 15;

    f32x4 acc[4][4];
    #pragma unroll
    for (int i = 0; i < 4; ++i)
        #pragma unroll
        for (int j = 0; j < 4; ++j) acc[i][j] = (f32x4){0.f, 0.f, 0.f, 0.f};

    for (int kt = 0; kt < K; kt += 32) {
        // --- stage A (fp32): 16 segs of 8 rows; lane covers 4 floats ---
        #pragma unroll
        for (int r = 0; r < 4; ++r) {
            int seg = r * 4 + wave;
            int rit = seg * 8 + (lane >> 3);
            int grow = min(row0 + rit, M - 1);
            const float* gp = A + (size_t)grow * K + kt + (lane & 7) * 4;
            gl2lds16(gp, &Asm[seg * 256]);
        }
        // --- stage Bt (bf16): 8 segs of 16 n-rows; lane covers 8 els ---
        #pragma unroll
        for (int r = 0; r < 2; ++r) {
            int seg = r * 4 + wave;
            int nit = seg * 16 + (lane >> 2);
            const ushort_t* gp = Bt + (size_t)(col0 + nit) * K + kt + (lane & 3) * 8;
            gl2lds16(gp, &Bsm[seg * 512]);
        }
        __syncthreads();
        s16x8 af[4], bfr[4];
        #pragma unroll
        for (int mi = 0; mi < 4; ++mi)
            af[mi] = cvt8(&Asm[(wm * 64 + mi * 16 + l15) * 32 + q4 * 8]);
        #pragma unroll
        for (int ni = 0; ni < 4; ++ni)
            bfr[ni] = *(const s16x8*)&Bsm[(wn * 64 + ni * 16 + l15) * 32 + q4 * 8];
        #pragma unroll
        for (int mi = 0; mi < 4; ++mi)
            #pragma unroll
            for (int ni = 0; ni < 4; ++ni)
                acc[mi][ni] = __builtin_amdgcn_mfma_f32_16x16x32_bf16(
                    af[mi], bfr[ni], acc[mi][ni], 0, 0, 0);
        __syncthreads();
    }
    // epilogue: C/D layout col=lane&15, row=quad*4+reg
    int colbase = col0 + wn * 64;                  // tile never straddles 768-seg
    int seg = colbase / DIM;
    int csub = colbase - seg * DIM;
    ushort_t* outp = (seg == 0) ? q : (seg == 1) ? kk : v;
    #pragma unroll
    for (int mi = 0; mi < 4; ++mi) {
        #pragma unroll
        for (int ni = 0; ni < 4; ++ni) {
            int gcol = colbase + ni * 16 + l15;
            int col  = csub + ni * 16 + l15;
            float bb = bias[gcol];
            #pragma unroll
            for (int j = 0; j < 4; ++j) {
                int row = row0 + wm * 64 + mi * 16 + q4 * 4 + j;
                if (row < M)
                    outp[(size_t)row * DIM + col] = f2bf(acc[mi][ni][j] + bb);
            }
        }
    }
}

// ---------------------------------------------------------------------------
// K6: out GEMM via MFMA. A = o bf16, Bt = W_out^T bf16 [768][768], C fp32.
// ---------------------------------------------------------------------------
__global__ __launch_bounds__(256)
void gemm_out_mfma(const ushort_t* __restrict__ A, const ushort_t* __restrict__ Bt,
                   const float* __restrict__ bias, float* __restrict__ C) {
    const int M = MROWS, N = DIM, K = DIM;
    __shared__ ushort_t Asm[128 * 32];   // 8 KB
    __shared__ ushort_t Bsm[128 * 32];   // 8 KB
    const int tid  = threadIdx.x;
    const int wave = tid >> 6;
    const int lane = tid & 63;
    const int row0 = blockIdx.y * 128;
    const int col0 = blockIdx.x * 128;
    const int wm = wave >> 1, wn = wave & 1;
    const int q4 = lane >> 4, l15 = lane & 15;

    f32x4 acc[4][4];
    #pragma unroll
    for (int i = 0; i < 4; ++i)
        #pragma unroll
        for (int j = 0; j < 4; ++j) acc[i][j] = (f32x4){0.f, 0.f, 0.f, 0.f};

    for (int kt = 0; kt < K; kt += 32) {
        #pragma unroll
        for (int r = 0; r < 2; ++r) {
            int seg = r * 4 + wave;
            int rit = seg * 16 + (lane >> 2);
            int grow = min(row0 + rit, M - 1);
            const ushort_t* gp = A + (size_t)grow * K + kt + (lane & 3) * 8;
            gl2lds16(gp, &Asm[seg * 512]);
        }
        #pragma unroll
        for (int r = 0; r < 2; ++r) {
            int seg = r * 4 + wave;
            int nit = seg * 16 + (lane >> 2);
            const ushort_t* gp = Bt + (size_t)(col0 + nit) * K + kt + (lane & 3) * 8;
            gl2lds16(gp, &Bsm[seg * 512]);
        }
        __syncthreads();
        s16x8 af[4], bfr[4];
        #pragma unroll
        for (int mi = 0; mi < 4; ++mi)
            af[mi] = *(const s16x8*)&Asm[(wm * 64 + mi * 16 + l15) * 32 + q4 * 8];
        #pragma unroll
        for (int ni = 0; ni < 4; ++ni)
            bfr[ni] = *(const s16x8*)&Bsm[(wn * 64 + ni * 16 + l15) * 32 + q4 * 8];
        #pragma unroll
        for (int mi = 0; mi < 4; ++mi)
            #pragma unroll
            for (int ni = 0; ni < 4; ++ni)
                acc[mi][ni] = __builtin_amdgcn_mfma_f32_16x16x32_bf16(
                    af[mi], bfr[ni], acc[mi][ni], 0, 0, 0);
        __syncthreads();
    }
    #pragma unroll
    for (int mi = 0; mi < 4; ++mi) {
        #pragma unroll
        for (int ni = 0; ni < 4; ++ni) {
            int col = col0 + wn * 64 + ni * 16 + l15;
            float bb = bias[col];
            #pragma unroll
            for (int j = 0; j < 4; ++j) {
                int row = row0 + wm * 64 + mi * 16 + q4 * 4 + j;
                if (row < M)
                    C[(size_t)row * N + col] = acc[mi][ni][j] + bb;
            }
        }
    }
}

// ---------------------------------------------------------------------------
// K2: per-(b,c) softmax stats over 785 tokens of k (bf16, row stride 768)
// ---------------------------------------------------------------------------
__global__ __launch_bounds__(256)
void softmax_stats_kernel(const bf16* __restrict__ k,
                          float* __restrict__ stat_m, float* __restrict__ stat_is) {
    int b = blockIdx.y;
    int c = blockIdx.x * 64 + threadIdx.x;
    int ty = threadIdx.y;
    const bf16* base = k + (size_t)b * NTOK * DIM + c;
    float m = -1e30f, s = 0.f;
    for (int n = ty; n < NTOK; n += 4) {
        float kv = __bfloat162float(base[(size_t)n * DIM]);
        float nm = fmaxf(m, kv);
        s = s * __expf(m - nm) + __expf(kv - nm);
        m = nm;
    }
    __shared__ float sm[4][64], ss[4][64];
    sm[ty][threadIdx.x] = m; ss[ty][threadIdx.x] = s;
    __syncthreads();
    if (ty == 0) {
        float M = sm[0][threadIdx.x];
        #pragma unroll
        for (int i = 1; i < 4; ++i) M = fmaxf(M, sm[i][threadIdx.x]);
        float S = 0.f;
        #pragma unroll
        for (int i = 0; i < 4; ++i) S += ss[i][threadIdx.x] * __expf(sm[i][threadIdx.x] - M);
        stat_m[b * DIM + c] = M;
        stat_is[b * DIM + c] = 1.f / S;
    }
}

// ---------------------------------------------------------------------------
// K3: attn[b,h,d,e] = sum_n softmax(k)[n,d] * v[n,e]   (96x96 per (b,h))
// ---------------------------------------------------------------------------
__global__ __launch_bounds__(256)
void attn_kernel(const bf16* __restrict__ k, const bf16* __restrict__ v,
                 const float* __restrict__ stat_m, const float* __restrict__ stat_is,
                 float* __restrict__ attn) {
    int h = blockIdx.x, b = blockIdx.y;
    int tx = threadIdx.x, ty = threadIdx.y;
    int t = ty * 16 + tx;
    __shared__ float ek[16][96], vv[16][96];
    __shared__ float smM[96], smIS[96];
    if (t < 96) { smM[t] = stat_m[b * DIM + h * HD + t]; smIS[t] = stat_is[b * DIM + h * HD + t]; }
    __syncthreads();
    float acc[6][6] = {};
    const bf16* kbase = k + (size_t)b * NTOK * DIM + h * HD;
    const bf16* vbase = v + (size_t)b * NTOK * DIM + h * HD;
    for (int n0 = 0; n0 < NTOK; n0 += 16) {
        #pragma unroll
        for (int i = 0; i < 6; ++i) {
            int idx = t + i * 256;
            int nl = idx / 96, c = idx % 96;
            int n = n0 + nl;
            float ekv = 0.f, vvv = 0.f;
            if (n < NTOK) {
                float kv = __bfloat162float(kbase[(size_t)n * DIM + c]);
                ekv = __expf(kv - smM[c]) * smIS[c];
                vvv = __bfloat162float(vbase[(size_t)n * DIM + c]);
            }
            ek[nl][c] = ekv; vv[nl][c] = vvv;
        }
        __syncthreads();
        #pragma unroll
        for (int nl = 0; nl < 16; ++nl) {
            float ka[6], vb[6];
            #pragma unroll
            for (int i = 0; i < 6; ++i) ka[i] = ek[nl][tx * 6 + i];
            #pragma unroll
            for (int j = 0; j < 6; ++j) vb[j] = vv[nl][ty * 6 + j];
            #pragma unroll
            for (int i = 0; i < 6; ++i)
                #pragma unroll
                for (int j = 0; j < 6; ++j)
                    acc[i][j] += ka[i] * vb[j];
        }
        __syncthreads();
    }
    float* abase = attn + ((size_t)(b * NH + h)) * HD * HD;
    #pragma unroll
    for (int i = 0; i < 6; ++i)
        #pragma unroll
        for (int j = 0; j < 6; ++j)
            abase[(size_t)(tx * 6 + i) * HD + ty * 6 + j] = acc[i][j];
}

// ---------------------------------------------------------------------------
// K4: depthwise-conv CRPE of v image tokens -> o[b,n,c] (rp, bf16); CLS -> 0
// ---------------------------------------------------------------------------
__global__ __launch_bounds__(256)
void crpe_kernel(const bf16* __restrict__ v,
                 const float* __restrict__ w3, const float* __restrict__ b3,
                 const float* __restrict__ w5, const float* __restrict__ b5,
                 const float* __restrict__ w7, const float* __restrict__ b7,
                 bf16* __restrict__ o) {
    int b = blockIdx.z;
    int y = blockIdx.y;
    int c = blockIdx.x * 64 + threadIdx.x;
    int ty = threadIdx.y;
    int ks; const float* wp; float bias;
    if (c < 192)      { ks = 3; wp = w3 + c * 9;          bias = b3[c]; }
    else if (c < 480) { ks = 5; wp = w5 + (c - 192) * 25; bias = b5[c - 192]; }
    else              { ks = 7; wp = w7 + (c - 480) * 49; bias = b7[c - 480]; }
    const bf16* vbase = v + (size_t)b * NTOK * DIM + c;
    bf16* obase = o + (size_t)b * NTOK * DIM + c;
    if (y == 0 && ty == 0) obase[0] = __float2bfloat16(0.f);
    int r = ks >> 1;
    for (int x = ty; x < GW; x += 4) {
        float acc = bias;
        for (int ky = 0; ky < ks; ++ky) {
            int yy = y + ky - r;
            if (yy < 0 || yy >= GH) continue;
            for (int kx = 0; kx < ks; ++kx) {
                int xx = x + kx - r;
                if (xx < 0 || xx >= GW) continue;
                acc += wp[ky * ks + kx] *
                       __bfloat162float(vbase[(size_t)(1 + yy * GW + xx) * DIM]);
            }
        }
        obase[(size_t)(1 + y * GW + x) * DIM] = __float2bfloat16(acc);
    }
}

// ---------------------------------------------------------------------------
// K5: o[b,n,h*96+e] = scale * sum_d q[n,d] attn[d,e] + q[n,e] * rp (in-place)
// ---------------------------------------------------------------------------
__global__ __launch_bounds__(256)
void combine_kernel(const bf16* __restrict__ q, const float* __restrict__ attn,
                    bf16* __restrict__ o) {
    int h = blockIdx.x;
    int n0 = blockIdx.y * 64;
    int b = blockIdx.z;
    int tx = threadIdx.x, ty = threadIdx.y;
    int t = ty * 16 + tx;
    __shared__ float as[96][96];
    __shared__ float qs[64][97];
    const float* abase = attn + ((size_t)(b * NH + h)) * HD * HD;
    #pragma unroll
    for (int i = 0; i < 36; ++i) {
        int idx = t + i * 256;
        as[idx / 96][idx % 96] = abase[idx];
    }
    const bf16* qbase = q + (size_t)b * NTOK * DIM + h * HD;
    #pragma unroll
    for (int i = 0; i < 24; ++i) {
        int idx = t + i * 256;
        int rr = idx / 96, cc = idx % 96;
        int n = n0 + rr;
        qs[rr][cc] = (n < NTOK) ? __bfloat162float(qbase[(size_t)n * DIM + cc]) : 0.f;
    }
    __syncthreads();
    float acc[4][6] = {};
    for (int d = 0; d < 96; ++d) {
        float qa[4], ab[6];
        #pragma unroll
        for (int i = 0; i < 4; ++i) qa[i] = qs[ty * 4 + i][d];
        #pragma unroll
        for (int j = 0; j < 6; ++j) ab[j] = as[d][tx * 6 + j];
        #pragma unroll
        for (int i = 0; i < 4; ++i)
            #pragma unroll
            for (int j = 0; j < 6; ++j)
                acc[i][j] += qa[i] * ab[j];
    }
    const float scale = 0.10206207261596575f;  // 96^-0.5
    bf16* obase = o + (size_t)b * NTOK * DIM + h * HD;
    #pragma unroll
    for (int i = 0; i < 4; ++i) {
        int n = n0 + ty * 4 + i;
        if (n >= NTOK) continue;
        #pragma unroll
        for (int j = 0; j < 6; ++j) {
            int e = tx * 6 + j;
            size_t oa = (size_t)n * DIM + e;
            float rp = __bfloat162float(obase[oa]);
            float qv = qs[ty * 4 + i][e];
            obase[oa] = __float2bfloat16(scale * acc[i][j] + qv * rp);
        }
    }
}

// ---------------------------------------------------------------------------
extern "C" void kernel_launch(void* const* d_in, const int* in_sizes, int n_in,
                              void* d_out, int out_size, void* d_ws, size_t ws_size,
                              hipStream_t stream) {
    const float* x     = (const float*)d_in[0];
    const float* W_qkv = (const float*)d_in[1];
    const float* b_qkv = (const float*)d_in[2];
    const float* W_out = (const float*)d_in[3];
    const float* b_out = (const float*)d_in[4];
    const float* w3    = (const float*)d_in[5];
    const float* cb3   = (const float*)d_in[6];
    const float* w5    = (const float*)d_in[7];
    const float* cb5   = (const float*)d_in[8];
    const float* w7    = (const float*)d_in[9];
    const float* cb7   = (const float*)d_in[10];
    float* out = (float*)d_out;

    // Workspace (130.3 MB):
    //   q,k,v  ushort M*768 each (38.6 MB)  [k aliased as o after attn_kernel]
    //   attn   f32  32*8*96*96  (9.4 MB)
    //   stats  f32  2*32*768    (0.4 MB)
    //   Wqkvt  ushort 2304*768  (3.5 MB)
    //   Wot    ushort 768*768   (1.2 MB)
    ushort_t* q = (ushort_t*)d_ws;
    ushort_t* k = q + (size_t)MROWS * DIM;
    ushort_t* v = k + (size_t)MROWS * DIM;
    float* attn    = (float*)(v + (size_t)MROWS * DIM);
    float* stat_m  = attn + (size_t)BN * NH * HD * HD;
    float* stat_is = stat_m + (size_t)BN * DIM;
    ushort_t* Wqkvt = (ushort_t*)(stat_is + (size_t)BN * DIM);
    ushort_t* Wot   = Wqkvt + (size_t)QKVD * DIM;
    ushort_t* o = k;   // alias: k dead after attn_kernel

    transpose_bf16_kernel<<<dim3(QKVD / 32, DIM / 32), dim3(32, 8), 0, stream>>>(
        W_qkv, Wqkvt, DIM, QKVD);
    transpose_bf16_kernel<<<dim3(DIM / 32, DIM / 32), dim3(32, 8), 0, stream>>>(
        W_out, Wot, DIM, DIM);
    gemm_qkv_mfma<<<dim3(QKVD / 128, (MROWS + 127) / 128), 256, 0, stream>>>(
        x, Wqkvt, b_qkv, q, k, v);
    softmax_stats_kernel<<<dim3(12, BN), dim3(64, 4), 0, stream>>>(
        (const bf16*)k, stat_m, stat_is);
    attn_kernel<<<dim3(NH, BN), dim3(16, 16), 0, stream>>>(
        (const bf16*)k, (const bf16*)v, stat_m, stat_is, attn);
    crpe_kernel<<<dim3(12, GH, BN), dim3(64, 4), 0, stream>>>(
        (const bf16*)v, w3, cb3, w5, cb5, w7, cb7, (bf16*)o);
    combine_kernel<<<dim3(NH, 13, BN), dim3(16, 16), 0, stream>>>(
        (const bf16*)q, attn, (bf16*)o);
    gemm_out_mfma<<<dim3(DIM / 128, (MROWS + 127) / 128), 256, 0, stream>>>(
        o, Wot, b_out, out);
}

// Round 4
// 1189.654 us; speedup vs baseline: 2.4217x; 1.4785x over previous
//
#include <hip/hip_runtime.h>
#include <hip/hip_bf16.h>
#include <math.h>

#define BN    32
#define NTOK  785
#define GH    28
#define GW    28
#define DIM   768
#define QKVD  2304
#define NH    8
#define HD    96
#define MROWS (BN*NTOK)   // 25120

typedef __hip_bfloat16 bf16;
typedef unsigned short ushort_t;
typedef short s16x8 __attribute__((ext_vector_type(8)));   // 8 bf16 = 4 VGPRs
typedef float f32x4 __attribute__((ext_vector_type(4)));   // MFMA acc

// ---------------------------------------------------------------------------
// helpers
// ---------------------------------------------------------------------------
__device__ __forceinline__ void gl2lds16(const void* g, void* l) {
    // 16B per lane, LDS dest = wave-uniform base + lane*16
    __builtin_amdgcn_global_load_lds(
        (__attribute__((address_space(1))) void*)const_cast<void*>(g),
        (__attribute__((address_space(3))) void*)l, 16, 0, 0);
}

__device__ __forceinline__ ushort_t f2bf(float f) {
    bf16 h = __float2bfloat16(f);
    return *(ushort_t*)&h;
}

__device__ __forceinline__ s16x8 cvt8(const float* p) {   // 8 fp32 (LDS) -> bf16x8
    float4 a = *(const float4*)p;
    float4 b = *(const float4*)(p + 4);
    union { s16x8 v; __hip_bfloat162 h[4]; } r;
    r.h[0] = __float22bfloat162_rn(make_float2(a.x, a.y));
    r.h[1] = __float22bfloat162_rn(make_float2(a.z, a.w));
    r.h[2] = __float22bfloat162_rn(make_float2(b.x, b.y));
    r.h[3] = __float22bfloat162_rn(make_float2(b.z, b.w));
    return r.v;
}

// ---------------------------------------------------------------------------
// K0: transpose-convert W[R][C] fp32 -> Wt[C][R] bf16
// ---------------------------------------------------------------------------
__global__ __launch_bounds__(256)
void transpose_bf16_kernel(const float* __restrict__ W, ushort_t* __restrict__ Wt,
                           int R, int C) {
    __shared__ float tile[32][33];
    int c0 = blockIdx.x * 32, r0 = blockIdx.y * 32;
    int tx = threadIdx.x, ty = threadIdx.y;   // 32 x 8
    #pragma unroll
    for (int i = 0; i < 4; ++i)
        tile[ty + i * 8][tx] = W[(size_t)(r0 + ty + i * 8) * C + c0 + tx];
    __syncthreads();
    #pragma unroll
    for (int i = 0; i < 4; ++i)
        Wt[(size_t)(c0 + ty + i * 8) * R + r0 + tx] = f2bf(tile[tx][ty + i * 8]);
}

// ---------------------------------------------------------------------------
// K1: qkv GEMM via MFMA. A = x fp32 (staged fp32, cvt on frag build),
// Bt = W_qkv^T bf16 [2304][768]. 128x128 tile, BK=32, 4 waves, 16x16x32 MFMA.
// ---------------------------------------------------------------------------
__global__ __launch_bounds__(256)
void gemm_qkv_mfma(const float* __restrict__ A, const ushort_t* __restrict__ Bt,
                   const float* __restrict__ bias,
                   ushort_t* __restrict__ q, ushort_t* __restrict__ kk,
                   ushort_t* __restrict__ v) {
    const int M = MROWS, K = DIM;
    __shared__ float    Asm[128 * 32];   // 16 KB, row-major [m][k]
    __shared__ ushort_t Bsm[128 * 32];   //  8 KB, row-major [n][k]
    const int tid  = threadIdx.x;
    const int wave = tid >> 6;
    const int lane = tid & 63;
    const int row0 = blockIdx.y * 128;
    const int col0 = blockIdx.x * 128;
    const int wm = wave >> 1, wn = wave & 1;
    const int q4 = lane >> 4, l15 = lane & 15;

    f32x4 acc[4][4];
    #pragma unroll
    for (int i = 0; i < 4; ++i)
        #pragma unroll
        for (int j = 0; j < 4; ++j) acc[i][j] = (f32x4){0.f, 0.f, 0.f, 0.f};

    for (int kt = 0; kt < K; kt += 32) {
        #pragma unroll
        for (int r = 0; r < 4; ++r) {
            int seg = r * 4 + wave;
            int rit = seg * 8 + (lane >> 3);
            int grow = min(row0 + rit, M - 1);
            const float* gp = A + (size_t)grow * K + kt + (lane & 7) * 4;
            gl2lds16(gp, &Asm[seg * 256]);
        }
        #pragma unroll
        for (int r = 0; r < 2; ++r) {
            int seg = r * 4 + wave;
            int nit = seg * 16 + (lane >> 2);
            const ushort_t* gp = Bt + (size_t)(col0 + nit) * K + kt + (lane & 3) * 8;
            gl2lds16(gp, &Bsm[seg * 512]);
        }
        __syncthreads();
        s16x8 af[4], bfr[4];
        #pragma unroll
        for (int mi = 0; mi < 4; ++mi)
            af[mi] = cvt8(&Asm[(wm * 64 + mi * 16 + l15) * 32 + q4 * 8]);
        #pragma unroll
        for (int ni = 0; ni < 4; ++ni)
            bfr[ni] = *(const s16x8*)&Bsm[(wn * 64 + ni * 16 + l15) * 32 + q4 * 8];
        #pragma unroll
        for (int mi = 0; mi < 4; ++mi)
            #pragma unroll
            for (int ni = 0; ni < 4; ++ni)
                acc[mi][ni] = __builtin_amdgcn_mfma_f32_16x16x32_bf16(
                    af[mi], bfr[ni], acc[mi][ni], 0, 0, 0);
        __syncthreads();
    }
    int colbase = col0 + wn * 64;
    int seg = colbase / DIM;
    int csub = colbase - seg * DIM;
    ushort_t* outp = (seg == 0) ? q : (seg == 1) ? kk : v;
    #pragma unroll
    for (int mi = 0; mi < 4; ++mi) {
        #pragma unroll
        for (int ni = 0; ni < 4; ++ni) {
            int gcol = colbase + ni * 16 + l15;
            int col  = csub + ni * 16 + l15;
            float bb = bias[gcol];
            #pragma unroll
            for (int j = 0; j < 4; ++j) {
                int row = row0 + wm * 64 + mi * 16 + q4 * 4 + j;
                if (row < M)
                    outp[(size_t)row * DIM + col] = f2bf(acc[mi][ni][j] + bb);
            }
        }
    }
}

// ---------------------------------------------------------------------------
// K6: out GEMM via MFMA. A = o bf16, Bt = W_out^T bf16, C fp32.
// ---------------------------------------------------------------------------
__global__ __launch_bounds__(256)
void gemm_out_mfma(const ushort_t* __restrict__ A, const ushort_t* __restrict__ Bt,
                   const float* __restrict__ bias, float* __restrict__ C) {
    const int M = MROWS, N = DIM, K = DIM;
    __shared__ ushort_t Asm[128 * 32];
    __shared__ ushort_t Bsm[128 * 32];
    const int tid  = threadIdx.x;
    const int wave = tid >> 6;
    const int lane = tid & 63;
    const int row0 = blockIdx.y * 128;
    const int col0 = blockIdx.x * 128;
    const int wm = wave >> 1, wn = wave & 1;
    const int q4 = lane >> 4, l15 = lane & 15;

    f32x4 acc[4][4];
    #pragma unroll
    for (int i = 0; i < 4; ++i)
        #pragma unroll
        for (int j = 0; j < 4; ++j) acc[i][j] = (f32x4){0.f, 0.f, 0.f, 0.f};

    for (int kt = 0; kt < K; kt += 32) {
        #pragma unroll
        for (int r = 0; r < 2; ++r) {
            int seg = r * 4 + wave;
            int rit = seg * 16 + (lane >> 2);
            int grow = min(row0 + rit, M - 1);
            const ushort_t* gp = A + (size_t)grow * K + kt + (lane & 3) * 8;
            gl2lds16(gp, &Asm[seg * 512]);
        }
        #pragma unroll
        for (int r = 0; r < 2; ++r) {
            int seg = r * 4 + wave;
            int nit = seg * 16 + (lane >> 2);
            const ushort_t* gp = Bt + (size_t)(col0 + nit) * K + kt + (lane & 3) * 8;
            gl2lds16(gp, &Bsm[seg * 512]);
        }
        __syncthreads();
        s16x8 af[4], bfr[4];
        #pragma unroll
        for (int mi = 0; mi < 4; ++mi)
            af[mi] = *(const s16x8*)&Asm[(wm * 64 + mi * 16 + l15) * 32 + q4 * 8];
        #pragma unroll
        for (int ni = 0; ni < 4; ++ni)
            bfr[ni] = *(const s16x8*)&Bsm[(wn * 64 + ni * 16 + l15) * 32 + q4 * 8];
        #pragma unroll
        for (int mi = 0; mi < 4; ++mi)
            #pragma unroll
            for (int ni = 0; ni < 4; ++ni)
                acc[mi][ni] = __builtin_amdgcn_mfma_f32_16x16x32_bf16(
                    af[mi], bfr[ni], acc[mi][ni], 0, 0, 0);
        __syncthreads();
    }
    #pragma unroll
    for (int mi = 0; mi < 4; ++mi) {
        #pragma unroll
        for (int ni = 0; ni < 4; ++ni) {
            int col = col0 + wn * 64 + ni * 16 + l15;
            float bb = bias[col];
            #pragma unroll
            for (int j = 0; j < 4; ++j) {
                int row = row0 + wm * 64 + mi * 16 + q4 * 4 + j;
                if (row < M)
                    C[(size_t)row * N + col] = acc[mi][ni][j] + bb;
            }
        }
    }
}

// ---------------------------------------------------------------------------
// K2: per-(b,c) softmax stats over 785 tokens of k
// ---------------------------------------------------------------------------
__global__ __launch_bounds__(256)
void softmax_stats_kernel(const bf16* __restrict__ k,
                          float* __restrict__ stat_m, float* __restrict__ stat_is) {
    int b = blockIdx.y;
    int c = blockIdx.x * 64 + threadIdx.x;
    int ty = threadIdx.y;
    const bf16* base = k + (size_t)b * NTOK * DIM + c;
    float m = -1e30f, s = 0.f;
    for (int n = ty; n < NTOK; n += 4) {
        float kv = __bfloat162float(base[(size_t)n * DIM]);
        float nm = fmaxf(m, kv);
        s = s * __expf(m - nm) + __expf(kv - nm);
        m = nm;
    }
    __shared__ float sm[4][64], ss[4][64];
    sm[ty][threadIdx.x] = m; ss[ty][threadIdx.x] = s;
    __syncthreads();
    if (ty == 0) {
        float M = sm[0][threadIdx.x];
        #pragma unroll
        for (int i = 1; i < 4; ++i) M = fmaxf(M, sm[i][threadIdx.x]);
        float S = 0.f;
        #pragma unroll
        for (int i = 0; i < 4; ++i) S += ss[i][threadIdx.x] * __expf(sm[i][threadIdx.x] - M);
        stat_m[b * DIM + c] = M;
        stat_is[b * DIM + c] = 1.f / S;
    }
}

// ---------------------------------------------------------------------------
// K3: attn[b,h,d,e] = sum_n softmax(k)[n,d] * v[n,e]
// ---------------------------------------------------------------------------
__global__ __launch_bounds__(256)
void attn_kernel(const bf16* __restrict__ k, const bf16* __restrict__ v,
                 const float* __restrict__ stat_m, const float* __restrict__ stat_is,
                 float* __restrict__ attn) {
    int h = blockIdx.x, b = blockIdx.y;
    int tx = threadIdx.x, ty = threadIdx.y;
    int t = ty * 16 + tx;
    __shared__ float ek[16][96], vv[16][96];
    __shared__ float smM[96], smIS[96];
    if (t < 96) { smM[t] = stat_m[b * DIM + h * HD + t]; smIS[t] = stat_is[b * DIM + h * HD + t]; }
    __syncthreads();
    float acc[6][6] = {};
    const bf16* kbase = k + (size_t)b * NTOK * DIM + h * HD;
    const bf16* vbase = v + (size_t)b * NTOK * DIM + h * HD;
    for (int n0 = 0; n0 < NTOK; n0 += 16) {
        #pragma unroll
        for (int i = 0; i < 6; ++i) {
            int idx = t + i * 256;
            int nl = idx / 96, c = idx % 96;
            int n = n0 + nl;
            float ekv = 0.f, vvv = 0.f;
            if (n < NTOK) {
                float kv = __bfloat162float(kbase[(size_t)n * DIM + c]);
                ekv = __expf(kv - smM[c]) * smIS[c];
                vvv = __bfloat162float(vbase[(size_t)n * DIM + c]);
            }
            ek[nl][c] = ekv; vv[nl][c] = vvv;
        }
        __syncthreads();
        #pragma unroll
        for (int nl = 0; nl < 16; ++nl) {
            float ka[6], vb[6];
            #pragma unroll
            for (int i = 0; i < 6; ++i) ka[i] = ek[nl][tx * 6 + i];
            #pragma unroll
            for (int j = 0; j < 6; ++j) vb[j] = vv[nl][ty * 6 + j];
            #pragma unroll
            for (int i = 0; i < 6; ++i)
                #pragma unroll
                for (int j = 0; j < 6; ++j)
                    acc[i][j] += ka[i] * vb[j];
        }
        __syncthreads();
    }
    float* abase = attn + ((size_t)(b * NH + h)) * HD * HD;
    #pragma unroll
    for (int i = 0; i < 6; ++i)
        #pragma unroll
        for (int j = 0; j < 6; ++j)
            abase[(size_t)(tx * 6 + i) * HD + ty * 6 + j] = acc[i][j];
}

// ---------------------------------------------------------------------------
// K4: CRPE depthwise conv, LDS-staged. Block = (cgroup64, half, batch).
// Stage 17 rows x 28 px x 64 ch bf16 = 59.5 KB LDS; each thread computes
// 2 channels (bfloat162 LDS reads) over 2 y-rows x 28 x.
// ---------------------------------------------------------------------------
template<int KS>
__device__ __forceinline__ void crpe_conv(const ushort_t* vimg, const float* wp,
                                          float bias0, float bias1,
                                          ushort_t* ob, int chp, int yq,
                                          int hf, int rowlo) {
    constexpr int R = KS / 2;
    float wA[KS * KS], wB[KS * KS];
    #pragma unroll
    for (int i = 0; i < KS * KS; ++i) { wA[i] = wp[i]; wB[i] = wp[KS * KS + i]; }
    #pragma unroll
    for (int yy0 = 0; yy0 < 2; ++yy0) {
        int yl = yq + yy0 * 8;
        if (yl >= 14) break;
        int y = hf * 14 + yl;
        for (int x = 0; x < GW; ++x) {
            float a0 = bias0, a1 = bias1;
            #pragma unroll
            for (int ky = 0; ky < KS; ++ky) {
                int gy = y + ky - R;
                if (gy < 0 || gy >= GH) continue;
                int ly = gy - rowlo;
                #pragma unroll
                for (int kx = 0; kx < KS; ++kx) {
                    int xx = x + kx - R;
                    if (xx < 0 || xx >= GW) continue;
                    __hip_bfloat162 pv =
                        *(const __hip_bfloat162*)&vimg[(ly * 28 + xx) * 64 + chp * 2];
                    float2 f = __bfloat1622float2(pv);
                    a0 = fmaf(wA[ky * KS + kx], f.x, a0);
                    a1 = fmaf(wB[ky * KS + kx], f.y, a1);
                }
            }
            *(__hip_bfloat162*)&ob[(size_t)(1 + y * GW + x) * DIM + chp * 2] =
                __float22bfloat162_rn(make_float2(a0, a1));
        }
    }
}

__global__ __launch_bounds__(256)
void crpe_lds_kernel(const ushort_t* __restrict__ v,
                     const float* __restrict__ w3, const float* __restrict__ b3,
                     const float* __restrict__ w5, const float* __restrict__ b5,
                     const float* __restrict__ w7, const float* __restrict__ b7,
                     ushort_t* __restrict__ o) {
    __shared__ ushort_t vimg[17 * 28 * 64];   // 60928 B
    const int cg  = blockIdx.x;    // 0..11 channel group
    const int hf  = blockIdx.y;    // 0..1 image half
    const int b   = blockIdx.z;
    const int tid = threadIdx.x;
    const int c0  = cg * 64;
    const int rowlo = hf ? 11 : 0;     // staged global rows rowlo..rowlo+16

    const ushort_t* vb = v + (size_t)b * NTOK * DIM + c0;
    for (int idx = tid; idx < 17 * 28 * 8; idx += 256) {
        int p8 = idx >> 3, c8 = idx & 7;
        int pix = rowlo * 28 + p8;     // global pixel (row-major, contiguous)
        *(s16x8*)&vimg[p8 * 64 + c8 * 8] =
            *(const s16x8*)(vb + (size_t)(1 + pix) * DIM + c8 * 8);
    }
    ushort_t* ob = o + (size_t)b * NTOK * DIM + c0;
    if (hf == 0 && tid < 64) ob[tid] = 0;   // CLS row: rp = 0 (bf16 zero bits)
    __syncthreads();

    const int chp = tid & 31;      // channel pair within group
    const int yq  = tid >> 5;      // 0..7 row phase
    const int ch0 = c0 + chp * 2;
    if (ch0 < 192)
        crpe_conv<3>(vimg, w3 + ch0 * 9, b3[ch0], b3[ch0 + 1], ob, chp, yq, hf, rowlo);
    else if (ch0 < 480)
        crpe_conv<5>(vimg, w5 + (ch0 - 192) * 25, b5[ch0 - 192], b5[ch0 - 191],
                     ob, chp, yq, hf, rowlo);
    else
        crpe_conv<7>(vimg, w7 + (ch0 - 480) * 49, b7[ch0 - 480], b7[ch0 - 479],
                     ob, chp, yq, hf, rowlo);
}

// ---------------------------------------------------------------------------
// K5: o[b,n,h*96+e] = scale * sum_d q[n,d] attn[d,e] + q[n,e] * rp (in-place)
// ---------------------------------------------------------------------------
__global__ __launch_bounds__(256)
void combine_kernel(const bf16* __restrict__ q, const float* __restrict__ attn,
                    bf16* __restrict__ o) {
    int h = blockIdx.x;
    int n0 = blockIdx.y * 64;
    int b = blockIdx.z;
    int tx = threadIdx.x, ty = threadIdx.y;
    int t = ty * 16 + tx;
    __shared__ float as[96][96];
    __shared__ float qs[64][97];
    const float* abase = attn + ((size_t)(b * NH + h)) * HD * HD;
    #pragma unroll
    for (int i = 0; i < 36; ++i) {
        int idx = t + i * 256;
        as[idx / 96][idx % 96] = abase[idx];
    }
    const bf16* qbase = q + (size_t)b * NTOK * DIM + h * HD;
    #pragma unroll
    for (int i = 0; i < 24; ++i) {
        int idx = t + i * 256;
        int rr = idx / 96, cc = idx % 96;
        int n = n0 + rr;
        qs[rr][cc] = (n < NTOK) ? __bfloat162float(qbase[(size_t)n * DIM + cc]) : 0.f;
    }
    __syncthreads();
    float acc[4][6] = {};
    for (int d = 0; d < 96; ++d) {
        float qa[4], ab[6];
        #pragma unroll
        for (int i = 0; i < 4; ++i) qa[i] = qs[ty * 4 + i][d];
        #pragma unroll
        for (int j = 0; j < 6; ++j) ab[j] = as[d][tx * 6 + j];
        #pragma unroll
        for (int i = 0; i < 4; ++i)
            #pragma unroll
            for (int j = 0; j < 6; ++j)
                acc[i][j] += qa[i] * ab[j];
    }
    const float scale = 0.10206207261596575f;  // 96^-0.5
    bf16* obase = o + (size_t)b * NTOK * DIM + h * HD;
    #pragma unroll
    for (int i = 0; i < 4; ++i) {
        int n = n0 + ty * 4 + i;
        if (n >= NTOK) continue;
        #pragma unroll
        for (int j = 0; j < 6; ++j) {
            int e = tx * 6 + j;
            size_t oa = (size_t)n * DIM + e;
            float rp = __bfloat162float(obase[oa]);
            float qv = qs[ty * 4 + i][e];
            obase[oa] = __float2bfloat16(scale * acc[i][j] + qv * rp);
        }
    }
}

// ---------------------------------------------------------------------------
extern "C" void kernel_launch(void* const* d_in, const int* in_sizes, int n_in,
                              void* d_out, int out_size, void* d_ws, size_t ws_size,
                              hipStream_t stream) {
    const float* x     = (const float*)d_in[0];
    const float* W_qkv = (const float*)d_in[1];
    const float* b_qkv = (const float*)d_in[2];
    const float* W_out = (const float*)d_in[3];
    const float* b_out = (const float*)d_in[4];
    const float* w3    = (const float*)d_in[5];
    const float* cb3   = (const float*)d_in[6];
    const float* w5    = (const float*)d_in[7];
    const float* cb5   = (const float*)d_in[8];
    const float* w7    = (const float*)d_in[9];
    const float* cb7   = (const float*)d_in[10];
    float* out = (float*)d_out;

    ushort_t* q = (ushort_t*)d_ws;
    ushort_t* k = q + (size_t)MROWS * DIM;
    ushort_t* v = k + (size_t)MROWS * DIM;
    float* attn    = (float*)(v + (size_t)MROWS * DIM);
    float* stat_m  = attn + (size_t)BN * NH * HD * HD;
    float* stat_is = stat_m + (size_t)BN * DIM;
    ushort_t* Wqkvt = (ushort_t*)(stat_is + (size_t)BN * DIM);
    ushort_t* Wot   = Wqkvt + (size_t)QKVD * DIM;
    ushort_t* o = k;   // alias: k dead after attn_kernel

    transpose_bf16_kernel<<<dim3(QKVD / 32, DIM / 32), dim3(32, 8), 0, stream>>>(
        W_qkv, Wqkvt, DIM, QKVD);
    transpose_bf16_kernel<<<dim3(DIM / 32, DIM / 32), dim3(32, 8), 0, stream>>>(
        W_out, Wot, DIM, DIM);
    gemm_qkv_mfma<<<dim3(QKVD / 128, (MROWS + 127) / 128), 256, 0, stream>>>(
        x, Wqkvt, b_qkv, q, k, v);
    softmax_stats_kernel<<<dim3(12, BN), dim3(64, 4), 0, stream>>>(
        (const bf16*)k, stat_m, stat_is);
    attn_kernel<<<dim3(NH, BN), dim3(16, 16), 0, stream>>>(
        (const bf16*)k, (const bf16*)v, stat_m, stat_is, attn);
    crpe_lds_kernel<<<dim3(12, 2, BN), 256, 0, stream>>>(
        v, w3, cb3, w5, cb5, w7, cb7, o);
    combine_kernel<<<dim3(NH, 13, BN), dim3(16, 16), 0, stream>>>(
        (const bf16*)q, attn, (bf16*)o);
    gemm_out_mfma<<<dim3(DIM / 128, (MROWS + 127) / 128), 256, 0, stream>>>(
        o, Wot, b_out, out);
}